// Round 4
// baseline (101.545 us; speedup 1.0000x reference)
//
#include <hip/hip_runtime.h>
#include <math.h>

// Problem constants (fixed by setup_inputs)
constexpr int B     = 64;
constexpr int D     = 1536;
constexpr int H     = 384;          // image H=W
constexpr int WS    = 16;           // window grid
constexpr int NW    = WS * WS;      // 256 windows per image
constexpr int SUB   = H / WS;       // 24 pixels per window side
constexpr int IMG   = H * H;        // 147456
constexpr int TOT   = B * IMG;      // 9437184 entropy elements
constexpr int TOTW  = B * NW;      // 16384 total windows

__device__ __forceinline__ float sig_entropy_f(float x) {
    float p  = 1.0f / (1.0f + __expf(-x));
    float pc = p < 1e-5f ? 1e-5f : p;
    return -p * __logf(pc);
}

// f64 entropy rounded to f32 (matches the verified R1/R3 precise semantics:
// the score is the f64 sum of the f32-rounded entropy values).
__device__ __forceinline__ double sig_entropy_d(double x) {
    double p  = 1.0 / (1.0 + exp(-x));
    double pc = p < 1e-5 ? 1e-5 : p;
    return (double)(float)(-p * log(pc));
}

// ---------------------------------------------------------------------------
// Fused entropy + pool + inline-precise. Block = (b, wy): a 24-row x 384-col
// band. 384 threads: col-group g = t%96 (4 consecutive cols, float4), row
// phase rr = t/96 (rows rr, rr+4, ..., rr+20). All loads/stores dwordx4,
// fully coalesced. Fast path: f32 entropy, f64 accumulation. Windows within
// 1e-4 of the threshold are recomputed in-block in f64 from register-held
// inputs (fast-vs-precise error ~1e-6, 100x inside the margin).
__global__ __launch_bounds__(384) void fused_kernel(
        const float* __restrict__ preds,
        float* __restrict__ ent,
        float* __restrict__ maskOut,
        unsigned char* __restrict__ flags) {
    __shared__ double part[384];
    __shared__ double pd[24];
    __shared__ int    bflag[16];

    int b  = blockIdx.x >> 4;
    int wy = blockIdx.x & 15;
    int t  = threadIdx.x;
    int g  = t % 96;                 // cols 4g .. 4g+3  (window wx = g/6)
    int rr = t / 96;                 // rows rr + 4k, k = 0..5

    const float4* p4 = (const float4*)preds;
    float4*       e4 = (float4*)ent;
    size_t base4 = ((size_t)b * IMG + (size_t)(wy * SUB) * H) / 4 + g;

    float4 xv[6];
    double s = 0.0;
#pragma unroll
    for (int k = 0; k < 6; ++k) {
        size_t idx = base4 + (size_t)(rr + 4 * k) * (H / 4);
        float4 v = p4[idx];
        xv[k] = v;
        float e0 = sig_entropy_f(v.x);
        float e1 = sig_entropy_f(v.y);
        float e2 = sig_entropy_f(v.z);
        float e3 = sig_entropy_f(v.w);
        e4[idx] = make_float4(e0, e1, e2, e3);
        s += (double)e0 + (double)e1 + (double)e2 + (double)e3;
    }
    part[t] = s;
    __syncthreads();

    if (t < WS) {
        double tot = 0.0;
        for (int rr2 = 0; rr2 < 4; ++rr2)
            for (int g2 = 0; g2 < 6; ++g2)
                tot += part[rr2 * 96 + t * 6 + g2];
        float score = (float)(tot / 576.0);
        float d = score - 0.299f;
        int sel = d > 0.0f ? 1 : 0;
        int w = b * NW + wy * WS + t;
        flags[w]   = (unsigned char)sel;
        maskOut[w] = sel ? 1.0f : 0.0f;
        bflag[t]   = (fabsf(d) < 1e-4f) ? 1 : 0;
    }
    __syncthreads();

    // Inline precise recompute of borderline windows (block-uniform branch:
    // bflag is LDS, same value for all threads -> syncthreads inside is safe).
    for (int wx = 0; wx < WS; ++wx) {
        if (!bflag[wx]) continue;
        if (g / 6 == wx) {           // the 24 threads owning this window
            double sd = 0.0;
#pragma unroll
            for (int k = 0; k < 6; ++k) {
                sd += sig_entropy_d((double)xv[k].x);
                sd += sig_entropy_d((double)xv[k].y);
                sd += sig_entropy_d((double)xv[k].z);
                sd += sig_entropy_d((double)xv[k].w);
            }
            pd[rr * 6 + (g % 6)] = sd;
        }
        __syncthreads();
        if (t == wx) {
            double tot = 0.0;
            for (int i = 0; i < 24; ++i) tot += pd[i];
            float score = (float)(tot / 576.0);
            int sel = (score > 0.299f) ? 1 : 0;
            int w = b * NW + wy * WS + wx;
            flags[w]   = (unsigned char)sel;
            maskOut[w] = sel ? 1.0f : 0.0f;
        }
        __syncthreads();
    }
}

// ---------------------------------------------------------------------------
// Scan: exclusive prefix over 16384 byte-flags; emits compact selected-window
// list + total count K. 1024 threads, 16 flags each (one uint4 load).
__global__ void scan_kernel(const unsigned char* __restrict__ flags,
                            int* __restrict__ list,
                            int* __restrict__ Kout) {
    int t    = threadIdx.x;
    int lane = t & 63, wave = t >> 6;
    uint4 raw = ((const uint4*)flags)[t];
    unsigned int wd[4] = {raw.x, raw.y, raw.z, raw.w};
    int v[16];
    int s = 0;
#pragma unroll
    for (int j = 0; j < 16; ++j) {
        v[j] = (wd[j >> 2] >> ((j & 3) * 8)) & 0xFF;
        s += v[j];
    }

    int x = s;
#pragma unroll
    for (int off = 1; off < 64; off <<= 1) {
        int y = __shfl_up(x, off, 64);
        if (lane >= off) x += y;
    }
    __shared__ int wsum[16];
    __shared__ int woff[16];
    if (lane == 63) wsum[wave] = x;
    __syncthreads();
    if (t == 0) {
        int a = 0;
        for (int i = 0; i < 16; ++i) { woff[i] = a; a += wsum[i]; }
    }
    __syncthreads();

    int excl = woff[wave] + x - s;
    int base = t * 16;
#pragma unroll
    for (int j = 0; j < 16; ++j) {
        if (v[j]) list[excl++] = base + j;
    }
    if (t == 0) *Kout = woff[15] + wsum[15];
}

// ---------------------------------------------------------------------------
// Gather: grid-stride over the compact list. 384 threads = one float4 per
// thread covers a 1536-float row exactly.
__global__ __launch_bounds__(384) void gather_kernel(
        const float* __restrict__ inF,
        const float* __restrict__ hIn,
        const int* __restrict__ list,
        const int* __restrict__ Kout,
        float* __restrict__ outL,
        float* __restrict__ outH,
        float* __restrict__ coords) {
    int Kv = *Kout;
    int t  = threadIdx.x;
    for (int k = blockIdx.x; k < Kv; k += gridDim.x) {
        int w  = list[k];
        int b  = w >> 8;
        int wi = w & 255;
        const float4* src_h = (const float4*)(hIn + (size_t)w * D);
        const float4* src_l = (const float4*)(inF + (size_t)b * D);
        float4* dst_h = (float4*)(outH + (size_t)k * D);
        float4* dst_l = (float4*)(outL + (size_t)k * D);
        dst_h[t] = src_h[t];
        dst_l[t] = src_l[t];
        if (t == 0) {
            coords[2 * (size_t)k]     = (float)(wi >> 4);
            coords[2 * (size_t)k + 1] = (float)(wi & 15);
        }
    }
}

// ---------------------------------------------------------------------------
extern "C" void kernel_launch(void* const* d_in, const int* in_sizes, int n_in,
                              void* d_out, int out_size, void* d_ws, size_t ws_size,
                              hipStream_t stream) {
    const float* input_features = (const float*)d_in[0];   // [B, D]
    const float* h_inputs       = (const float*)d_in[1];   // [B, NW, D]
    const float* preds          = (const float*)d_in[2];   // [B, 1, H, H]
    float* out = (float*)d_out;

    // out layout: l[K,D] | h[K,D] | mask[TOTW] | coords[K,2] | entropy[TOT]
    int K = (out_size - TOT - TOTW) / (2 * D + 2);
    float* outL      = out;
    float* outH      = out + (size_t)K * D;
    float* outMask   = out + (size_t)2 * K * D;
    float* outCoords = outMask + TOTW;
    float* outEnt    = outCoords + (size_t)2 * K;

    // ws layout (80.004 KB, well inside the 128 KB proven safe in R1):
    //   flags uchar[16384] | list int[16384] | Kout int[1]
    unsigned char* flags = (unsigned char*)d_ws;
    int* list = (int*)(flags + TOTW);
    int* Kout = list + TOTW;

    fused_kernel<<<B * WS, 384, 0, stream>>>(preds, outEnt, outMask, flags);
    scan_kernel<<<1, 1024, 0, stream>>>(flags, list, Kout);
    gather_kernel<<<2048, 384, 0, stream>>>(input_features, h_inputs, list, Kout,
                                            outL, outH, outCoords);
}

// Round 5
// 91.100 us; speedup vs baseline: 1.1147x; 1.1147x over previous
//
#include <hip/hip_runtime.h>
#include <math.h>

// Problem constants (fixed by setup_inputs)
constexpr int B     = 64;
constexpr int D     = 1536;
constexpr int H     = 384;          // image H=W
constexpr int WS    = 16;           // window grid
constexpr int NW    = WS * WS;      // 256 windows per image
constexpr int SUB   = H / WS;       // 24 pixels per window side
constexpr int IMG   = H * H;        // 147456
constexpr int TOT   = B * IMG;      // 9437184 entropy elements
constexpr int TOTW  = B * NW;       // 16384 total windows

__device__ __forceinline__ float sig_entropy_f(float x) {
    float p  = 1.0f / (1.0f + __expf(-x));
    float pc = p < 1e-5f ? 1e-5f : p;
    return -p * __logf(pc);
}

// f64 entropy rounded to f32 (the verified R1/R3 precise semantics: score is
// the f64 sum of the f32-rounded entropy values).
__device__ __forceinline__ double sig_entropy_d(double x) {
    double p  = 1.0 / (1.0 + exp(-x));
    double pc = p < 1e-5 ? 1e-5 : p;
    return (double)(float)(-p * log(pc));
}

// ---------------------------------------------------------------------------
// Fused entropy + pool. Block = (b, wy): 24-row x 384-col band. 384 threads:
// col-group g = t%96 (4 cols, float4), row phase rr = t/96 (rows rr+4k).
// All global accesses dwordx4 coalesced. LOW VGPR: nothing cached across the
// barrier, no f64 transcendentals here. Borderline windows (|score-thr|<1e-4)
// get bit 1 set in their flag byte for the precise kernel.
__global__ __launch_bounds__(384) void fused_kernel(
        const float* __restrict__ preds,
        float* __restrict__ ent,
        float* __restrict__ maskOut,
        unsigned char* __restrict__ flags) {
    __shared__ double part[384];

    int b  = blockIdx.x >> 4;
    int wy = blockIdx.x & 15;
    int t  = threadIdx.x;
    int g  = t % 96;                 // cols 4g..4g+3  (window wx = g/6)
    int rr = t / 96;                 // rows rr + 4k, k = 0..5

    const float4* p4 = (const float4*)preds;
    float4*       e4 = (float4*)ent;
    size_t base4 = ((size_t)b * IMG + (size_t)(wy * SUB) * H) / 4 + g;

    double s = 0.0;
#pragma unroll
    for (int k = 0; k < 6; ++k) {
        size_t idx = base4 + (size_t)(rr + 4 * k) * (H / 4);
        float4 v = p4[idx];
        float e0 = sig_entropy_f(v.x);
        float e1 = sig_entropy_f(v.y);
        float e2 = sig_entropy_f(v.z);
        float e3 = sig_entropy_f(v.w);
        e4[idx] = make_float4(e0, e1, e2, e3);
        s += (double)e0 + (double)e1 + (double)e2 + (double)e3;
    }
    part[t] = s;
    __syncthreads();

    if (t < WS) {
        double tot = 0.0;
        for (int rr2 = 0; rr2 < 4; ++rr2)
            for (int g2 = 0; g2 < 6; ++g2)
                tot += part[rr2 * 96 + t * 6 + g2];
        float score = (float)(tot / 576.0);
        float d = score - 0.299f;
        int sel = d > 0.0f ? 1 : 0;
        int w = b * NW + wy * WS + t;
        unsigned char f = (unsigned char)sel;
        if (fabsf(d) < 1e-4f) f |= 2;    // borderline -> precise pass decides
        flags[w]   = f;
        maskOut[w] = sel ? 1.0f : 0.0f;  // provisional; precise may overwrite
    }
}

// ---------------------------------------------------------------------------
// Precise: 256 blocks x 64 lanes; block j owns windows 64j..64j+63. Ballot
// finds borderline windows; the whole wave recomputes each in f64 (R1-verified
// arithmetic) and overwrites flag+mask, clearing the borderline bit.
__global__ __launch_bounds__(64) void precise_kernel(
        const float* __restrict__ preds,
        float* __restrict__ maskOut,
        unsigned char* __restrict__ flags) {
    int lane  = threadIdx.x;
    int wbase = blockIdx.x * 64;
    unsigned char myf = flags[wbase + lane];
    unsigned long long bl = __ballot(myf & 2);
    while (bl) {
        int bit = __ffsll(bl) - 1;
        bl &= bl - 1;
        int w  = wbase + bit;
        int bb = w >> 8;
        int wi = w & 255;
        int wy = wi >> 4, wx = wi & 15;
        const float* basep = preds + (size_t)bb * IMG + (size_t)(wy * SUB) * H + wx * SUB;
        double s = 0.0;
        for (int e = lane; e < SUB * SUB; e += 64) {
            int r = e / SUB, c = e % SUB;
            s += sig_entropy_d((double)basep[r * H + c]);
        }
        for (int off = 32; off > 0; off >>= 1)
            s += __shfl_down(s, off, 64);
        if (lane == 0) {
            float score = (float)(s / 576.0);
            int sel = (score > 0.299f) ? 1 : 0;
            flags[w]   = (unsigned char)sel;
            maskOut[w] = sel ? 1.0f : 0.0f;
        }
    }
}

// ---------------------------------------------------------------------------
// Scan: exclusive prefix over 16384 byte-flags; emits compact selected-window
// list + total count K. 1024 threads, 16 flags each (one uint4 load).
__global__ void scan_kernel(const unsigned char* __restrict__ flags,
                            int* __restrict__ list,
                            int* __restrict__ Kout) {
    int t    = threadIdx.x;
    int lane = t & 63, wave = t >> 6;
    uint4 raw = ((const uint4*)flags)[t];
    unsigned int wd[4] = {raw.x, raw.y, raw.z, raw.w};
    int v[16];
    int s = 0;
#pragma unroll
    for (int j = 0; j < 16; ++j) {
        v[j] = (wd[j >> 2] >> ((j & 3) * 8)) & 0xFF;
        s += v[j];
    }

    int x = s;
#pragma unroll
    for (int off = 1; off < 64; off <<= 1) {
        int y = __shfl_up(x, off, 64);
        if (lane >= off) x += y;
    }
    __shared__ int wsum[16];
    __shared__ int woff[16];
    if (lane == 63) wsum[wave] = x;
    __syncthreads();
    if (t == 0) {
        int a = 0;
        for (int i = 0; i < 16; ++i) { woff[i] = a; a += wsum[i]; }
    }
    __syncthreads();

    int excl = woff[wave] + x - s;
    int base = t * 16;
#pragma unroll
    for (int j = 0; j < 16; ++j) {
        if (v[j]) list[excl++] = base + j;
    }
    if (t == 0) *Kout = woff[15] + wsum[15];
}

// ---------------------------------------------------------------------------
// Gather: grid-stride over the compact list. 384 threads = one float4 per
// thread covers a 1536-float row exactly.
__global__ __launch_bounds__(384) void gather_kernel(
        const float* __restrict__ inF,
        const float* __restrict__ hIn,
        const int* __restrict__ list,
        const int* __restrict__ Kout,
        float* __restrict__ outL,
        float* __restrict__ outH,
        float* __restrict__ coords) {
    int Kv = *Kout;
    int t  = threadIdx.x;
    for (int k = blockIdx.x; k < Kv; k += gridDim.x) {
        int w  = list[k];
        int b  = w >> 8;
        int wi = w & 255;
        const float4* src_h = (const float4*)(hIn + (size_t)w * D);
        const float4* src_l = (const float4*)(inF + (size_t)b * D);
        float4* dst_h = (float4*)(outH + (size_t)k * D);
        float4* dst_l = (float4*)(outL + (size_t)k * D);
        dst_h[t] = src_h[t];
        dst_l[t] = src_l[t];
        if (t == 0) {
            coords[2 * (size_t)k]     = (float)(wi >> 4);
            coords[2 * (size_t)k + 1] = (float)(wi & 15);
        }
    }
}

// ---------------------------------------------------------------------------
extern "C" void kernel_launch(void* const* d_in, const int* in_sizes, int n_in,
                              void* d_out, int out_size, void* d_ws, size_t ws_size,
                              hipStream_t stream) {
    const float* input_features = (const float*)d_in[0];   // [B, D]
    const float* h_inputs       = (const float*)d_in[1];   // [B, NW, D]
    const float* preds          = (const float*)d_in[2];   // [B, 1, H, H]
    float* out = (float*)d_out;

    // out layout: l[K,D] | h[K,D] | mask[TOTW] | coords[K,2] | entropy[TOT]
    int K = (out_size - TOT - TOTW) / (2 * D + 2);
    float* outL      = out;
    float* outH      = out + (size_t)K * D;
    float* outMask   = out + (size_t)2 * K * D;
    float* outCoords = outMask + TOTW;
    float* outEnt    = outCoords + (size_t)2 * K;

    // ws layout (~80 KB, inside the 128 KB proven safe in R1):
    //   flags uchar[16384] | list int[16384] | Kout int[1]
    unsigned char* flags = (unsigned char*)d_ws;
    int* list = (int*)(flags + TOTW);
    int* Kout = list + TOTW;

    fused_kernel<<<B * WS, 384, 0, stream>>>(preds, outEnt, outMask, flags);
    precise_kernel<<<TOTW / 64, 64, 0, stream>>>(preds, outMask, flags);
    scan_kernel<<<1, 1024, 0, stream>>>(flags, list, Kout);
    gather_kernel<<<2048, 384, 0, stream>>>(input_features, h_inputs, list, Kout,
                                            outL, outH, outCoords);
}

// Round 7
// 73.867 us; speedup vs baseline: 1.3747x; 1.2333x over previous
//
#include <hip/hip_runtime.h>
#include <math.h>

// Problem constants (fixed by setup_inputs)
constexpr int B     = 64;
constexpr int D     = 1536;
constexpr int H     = 384;          // image H=W
constexpr int WS    = 16;           // window grid
constexpr int NW    = WS * WS;      // 256 windows per image
constexpr int SUB   = H / WS;       // 24 pixels per window side
constexpr int IMG   = H * H;        // 147456
constexpr int TOT   = B * IMG;      // 9437184 entropy elements
constexpr int TOTW  = B * NW;       // 16384 total windows
constexpr int NBAND = B * WS;       // 1024 bands of 24 rows

__device__ __forceinline__ float sig_entropy_f(float x) {
    float p  = 1.0f / (1.0f + __expf(-x));
    float pc = p < 1e-5f ? 1e-5f : p;
    return -p * __logf(pc);
}

// f64 entropy rounded to f32 (the verified R1/R3/R5 precise semantics: score
// is the f64 sum of f32-rounded entropy values).
__device__ __forceinline__ double sig_entropy_d(double x) {
    double p  = 1.0 / (1.0 + exp(-x));
    double pc = p < 1e-5 ? 1e-5 : p;
    return (double)(float)(-p * log(pc));
}

// ---------------------------------------------------------------------------
// K1: fused entropy + pool + inline-precise. Block = band (b, wy): 24 rows x
// 384 cols. 384 threads: col-group g = t%96 (4 cols, float4), row phase
// rr = t/96 (rows rr+4k). All global accesses dwordx4 coalesced. Fast path:
// f32 entropy, f64 accumulation. Borderline windows (|score-0.299|<1e-4,
// ~0.27 per block) recomputed inline in f64 re-reading preds from global
// (L2-hot) -- no register caching across barriers (R4's regression).
__global__ __launch_bounds__(384, 3) void fused_kernel(
        const float* __restrict__ preds,
        float* __restrict__ ent,
        float* __restrict__ maskOut,
        unsigned char* __restrict__ flags) {
    __shared__ double part[384];
    __shared__ double warr[6];
    __shared__ int    bflag[16];

    const int band = blockIdx.x;
    const int b    = band >> 4;
    const int wy   = band & 15;
    const int t    = threadIdx.x;
    const int lane = t & 63;
    const int wv   = t >> 6;
    const int g    = t % 96;          // cols 4g..4g+3  (window wx = g/6)
    const int rr   = t / 96;          // rows rr + 4k, k = 0..5

    const float4* p4 = (const float4*)preds;
    float4*       e4 = (float4*)ent;
    size_t base4 = ((size_t)b * IMG + (size_t)(wy * SUB) * H) / 4 + g;

    double s = 0.0;
#pragma unroll
    for (int k = 0; k < 6; ++k) {
        size_t idx = base4 + (size_t)(rr + 4 * k) * (H / 4);
        float4 v = p4[idx];
        float e0 = sig_entropy_f(v.x);
        float e1 = sig_entropy_f(v.y);
        float e2 = sig_entropy_f(v.z);
        float e3 = sig_entropy_f(v.w);
        e4[idx] = make_float4(e0, e1, e2, e3);
        s += (double)e0 + (double)e1 + (double)e2 + (double)e3;
    }
    part[t] = s;
    __syncthreads();

    if (t < WS) {
        double tot = 0.0;
        for (int rr2 = 0; rr2 < 4; ++rr2)
            for (int g2 = 0; g2 < 6; ++g2)
                tot += part[rr2 * 96 + t * 6 + g2];
        float score = (float)(tot / 576.0);
        float d = score - 0.299f;
        int sel = d > 0.0f ? 1 : 0;
        int w = b * NW + wy * WS + t;
        flags[w]   = (unsigned char)sel;
        maskOut[w] = sel ? 1.0f : 0.0f;      // provisional
        bflag[t]   = (fabsf(d) < 1e-4f) ? 1 : 0;
    }
    __syncthreads();

    // Inline f64 recompute of borderline windows (bflag is LDS-uniform, so
    // the branch is block-uniform and the inner __syncthreads are safe).
    for (int wx = 0; wx < WS; ++wx) {
        if (!bflag[wx]) continue;
        const float* basep = preds + (size_t)b * IMG
                           + (size_t)(wy * SUB) * H + wx * SUB;
        // 576 elements: e = t (0..383) and e = t+384 (t<192)
        int r0 = t / SUB, c0 = t % SUB;
        double sd = sig_entropy_d((double)basep[r0 * H + c0]);
        if (t < 192) {
            int e2i = t + 384;
            int r1 = e2i / SUB, c1 = e2i % SUB;
            sd += sig_entropy_d((double)basep[r1 * H + c1]);
        }
        for (int off = 32; off > 0; off >>= 1)
            sd += __shfl_down(sd, off, 64);
        if (lane == 0) warr[wv] = sd;
        __syncthreads();
        if (t == 0) {
            double tot = 0.0;
            for (int i = 0; i < 6; ++i) tot += warr[i];
            float score = (float)(tot / 576.0);
            int sel = (score > 0.299f) ? 1 : 0;
            int w = b * NW + wy * WS + wx;
            flags[w]   = (unsigned char)sel;
            maskOut[w] = sel ? 1.0f : 0.0f;
        }
        __syncthreads();
    }
}

// ---------------------------------------------------------------------------
// K2: scan + gather in one kernel. Every block redundantly scans the 16 KB
// flag array (L2-hot after K1's kernel-boundary flush): LDS copy, 64-byte
// chunk popcounts, 4-wave block scan -> exclusive chunk prefixes + total K.
// Then grid-stride over compacted slots k; thread 0 maps slot->window via
// binary search over chunk prefixes + bit-walk, block copies the rows.
__global__ __launch_bounds__(384) void scan_gather_kernel(
        const float* __restrict__ inF,
        const float* __restrict__ hIn,
        const unsigned char* __restrict__ flags,
        float* __restrict__ outL,
        float* __restrict__ outH,
        float* __restrict__ coords) {
    __shared__ uint4 flv[TOTW / 16];     // 16 KB flag copy
    __shared__ int   cpref[257];         // exclusive chunk prefixes + total
    __shared__ int   wsum4[4];
    __shared__ int   woff4[4];
    __shared__ int   sw;

    unsigned char* fl = (unsigned char*)flv;
    const int t    = threadIdx.x;
    const int lane = t & 63;
    const int wv   = t >> 6;

    for (int j = t; j < TOTW / 16; j += 384)
        flv[j] = ((const uint4*)flags)[j];
    __syncthreads();

    int partial = 0;
    if (t < 256) {
        const unsigned int* p = (const unsigned int*)(fl + t * 64);
#pragma unroll
        for (int j = 0; j < 16; ++j) {
            unsigned int wd = p[j];
            partial += (int)(((wd & 0x01010101u) * 0x01010101u) >> 24);
        }
    }
    int x = partial;
#pragma unroll
    for (int off = 1; off < 64; off <<= 1) {
        int y = __shfl_up(x, off, 64);
        if (lane >= off) x += y;
    }
    if (t < 256 && lane == 63) wsum4[wv] = x;
    __syncthreads();
    if (t == 0) {
        int a = 0;
        for (int i = 0; i < 4; ++i) { woff4[i] = a; a += wsum4[i]; }
        cpref[256] = a;
    }
    __syncthreads();
    if (t < 256) cpref[t] = woff4[wv] + x - partial;
    __syncthreads();

    const int Kv = cpref[256];
    for (int k = blockIdx.x; k < Kv; k += gridDim.x) {
        if (t == 0) {
            int lo = 0, hi = 255;           // largest c with cpref[c] <= k
            while (lo < hi) {
                int mid = (lo + hi + 1) >> 1;
                if (cpref[mid] <= k) lo = mid; else hi = mid - 1;
            }
            int r = k - cpref[lo];
            int basei = lo * 64;
            int w = basei;
            for (int j = 0; j < 64; ++j) {
                if (fl[basei + j]) {
                    if (r == 0) { w = basei + j; break; }
                    --r;
                }
            }
            sw = w;
        }
        __syncthreads();
        const int w  = sw;
        const int b  = w >> 8;
        const int wi = w & 255;
        const float4* src_h = (const float4*)(hIn + (size_t)w * D);
        const float4* src_l = (const float4*)(inF + (size_t)b * D);
        float4* dst_h = (float4*)(outH + (size_t)k * D);
        float4* dst_l = (float4*)(outL + (size_t)k * D);
        dst_h[t] = src_h[t];
        dst_l[t] = src_l[t];
        if (t == 0) {
            coords[2 * (size_t)k]     = (float)(wi >> 4);
            coords[2 * (size_t)k + 1] = (float)(wi & 15);
        }
        __syncthreads();   // sw consumed by all before next overwrite
    }
}

// ---------------------------------------------------------------------------
extern "C" void kernel_launch(void* const* d_in, const int* in_sizes, int n_in,
                              void* d_out, int out_size, void* d_ws, size_t ws_size,
                              hipStream_t stream) {
    const float* input_features = (const float*)d_in[0];   // [B, D]
    const float* h_inputs       = (const float*)d_in[1];   // [B, NW, D]
    const float* preds          = (const float*)d_in[2];   // [B, 1, H, H]
    float* out = (float*)d_out;

    // out layout: l[K,D] | h[K,D] | mask[TOTW] | coords[K,2] | entropy[TOT]
    int K = (out_size - TOT - TOTW) / (2 * D + 2);
    float* outL      = out;
    float* outH      = out + (size_t)K * D;
    float* outMask   = out + (size_t)2 * K * D;
    float* outCoords = outMask + TOTW;
    float* outEnt    = outCoords + (size_t)2 * K;

    // ws layout: flags uchar[16384] (16 KB, far inside the proven-safe 128 KB)
    unsigned char* flags = (unsigned char*)d_ws;

    fused_kernel<<<NBAND, 384, 0, stream>>>(preds, outEnt, outMask, flags);
    scan_gather_kernel<<<1024, 384, 0, stream>>>(input_features, h_inputs, flags,
                                                 outL, outH, outCoords);
}